// Round 12
// baseline (278.686 us; speedup 1.0000x reference)
//
#include <hip/hip_runtime.h>
#include <hip/hip_bf16.h>

typedef __attribute__((ext_vector_type(8))) short short8;
typedef __attribute__((ext_vector_type(4))) float f32x4;

static constexpr int NN = 64;
static constexpr int C  = 128;
static constexpr int H  = 56;
static constexpr int W  = 56;
static constexpr int HP = 58;               // padded spatial extent
// X/Y1 plane layout: [n][y(58)][ks(4)][x(58)][32ch bf16]
static constexpr int PLB  = 58 * 64;        // plane bytes  (3712)
static constexpr int ROWB2 = 4 * PLB;       // row bytes    (14848)
static constexpr int NB   = 58 * ROWB2;     // n bytes      (861184)

__device__ __forceinline__ void gload16(const void* g, void* l) {
    __builtin_amdgcn_global_load_lds(
        (const __attribute__((address_space(1))) unsigned int*)g,
        (__attribute__((address_space(3))) unsigned int*)l, 16, 0, 0);
}

__device__ __forceinline__ f32x4 mfma16(short8 a, short8 b, f32x4 c) {
    return __builtin_amdgcn_mfma_f32_16x16x32_bf16(a, b, c, 0, 0, 0);
}

// ---------------------------------------------------------------------------
// Pack weights into 16x16x32 MFMA B-fragment order (verified R9-R11).
// Fragment f = (tap*4 + ks)*8 + ob, 1024 B each; K-step = contiguous 8 KB.
// ---------------------------------------------------------------------------
__global__ __launch_bounds__(128)
void pack_weights(const float* __restrict__ w, const float* __restrict__ g,
                  const float* __restrict__ b, const float* __restrict__ m,
                  const float* __restrict__ v, __hip_bfloat16* __restrict__ Wp,
                  float* __restrict__ shift)
{
    int o = blockIdx.x;
    int c = threadIdx.x;
    float scale = g[o] * rsqrtf(v[o] + 1e-5f);
    if (c == 0) shift[o] = b[o] - m[o] * scale;
    const float* ws = w + ((size_t)o * C + c) * 9;
    int ks = c >> 5, lane = (o & 15) | (((c >> 3) & 3) << 4), jj = c & 7;
    int ob = o >> 4;
    #pragma unroll
    for (int tap = 0; tap < 9; ++tap) {
        size_t f = (size_t)(tap * 4 + ks) * 8 + ob;
        Wp[f * 512 + lane * 8 + jj] = __float2bfloat16(ws[tap] * scale);
    }
}

// ---------------------------------------------------------------------------
// NCHW fp32 -> padded ks-plane bf16:  Xp[n][y][ks][x][32c], y=h+1, x=w+1.
// ---------------------------------------------------------------------------
__global__ __launch_bounds__(256)
void transform_x(const float* __restrict__ x, char* __restrict__ Xp)
{
    __shared__ float t[C * 57];
    int bid = blockIdx.x;
    int n = bid / H, h = bid % H;
    int tid = threadIdx.x;

    #pragma unroll
    for (int i = 0; i < 7; ++i) {
        int idx4 = i * 256 + tid;
        int c  = idx4 / 14;
        int wq = (idx4 % 14) * 4;
        const float* p = x + ((size_t)(n * C + c)) * (H * W) + h * W + wq;
        float4 vv = *(const float4*)p;
        t[c * 57 + wq + 0] = vv.x;
        t[c * 57 + wq + 1] = vv.y;
        t[c * 57 + wq + 2] = vv.z;
        t[c * 57 + wq + 3] = vv.w;
    }
    __syncthreads();
    char* rowb = Xp + (size_t)n * NB + (size_t)(h + 1) * ROWB2;
    #pragma unroll
    for (int i = 0; i < 28; ++i) {
        int idx = i * 256 + tid;
        int c = idx & 127, w = idx >> 7;
        float vv = t[c * 57 + w];
        int ks = c >> 5, cc = c & 31;
        *(__hip_bfloat16*)(rowb + ks * PLB + (w + 1) * 64 + cc * 2) =
            __float2bfloat16(vv);
    }
}

// ---------------------------------------------------------------------------
// Zero the halo of a plane-layout buffer: rows y=0,57 fully; cols x=0,57.
// Per n: 1856 row units + 1792 col units = 3648 x 16B.  Grid 912 x 256.
// ---------------------------------------------------------------------------
__global__ __launch_bounds__(256)
void zero_halo(char* __restrict__ buf)
{
    int idx = blockIdx.x * 256 + threadIdx.x;
    int n = idx / 3648, u = idx % 3648;
    int y, ks, x, q;
    if (u < 1856) {
        y = (u < 928) ? 0 : 57;
        int up = u % 928;
        ks = up / 232;
        int u2 = up % 232;
        x = u2 >> 2; q = u2 & 3;
    } else {
        int v = u - 1856;
        y = 1 + v / 32;
        int vp = v % 32;
        ks = vp >> 3;
        int v2 = vp & 7;
        x = (v2 >> 2) * 57; q = v2 & 3;
    }
    char* dst = buf + (size_t)n * NB + (size_t)y * ROWB2 + ks * PLB + x * 64 + q * 16;
    *(short8*)dst = short8{0,0,0,0,0,0,0,0};
}

// ---------------------------------------------------------------------------
// Implicit-GEMM 3x3 conv, X-from-global / W-in-LDS, occupancy-first.
// Block = 512 thr (8 waves), 2 output rows x O=128.
// Wave (wm,mh,oh): row h0+wm, m in [mh*32,+32), o in [oh*64,+64),
// acc[2][4] f32x4 = 32 regs (math verified R9-R11).
// X: NO LDS — A-fragment is one coalesced 1KB global load from the ks-plane
//    layout (lanes (lr,lg) cover [0,1024) exactly; L1-resident per step).
//    Out-of-plane overrun (pos>=58) feeds only masked m>=56 lanes.
// W: LDS triple-buffer of 8 KB K-step tiles, 2-body prefetch.  Per body:
//    {xa global loads; stage W(s+2); [compiler vmcnt(1) for xa retires
//     W(s+1)]; MFMA (setprio); raw s_barrier}.  No drain-to-0 anywhere;
//    each wave retires its own stage contribution before its barrier.
// LDS total 24.6 KB -> 4 blocks/CU by wave slots; target ~28 waves/CU.
// WHICH==0: D[m][o] -> relu(D+shift) -> plane-layout bf16 (Y1)
// WHICH==1: D[o][m] -> relu(D+shift+identity) -> NCHW fp32
// ---------------------------------------------------------------------------
template<int WHICH>
__global__ __launch_bounds__(512, 2)
void conv3x3_kernel(const char* __restrict__ Xp,
                    const __hip_bfloat16* __restrict__ Wp,
                    const float* __restrict__ shift,
                    const float* __restrict__ ident,
                    void* __restrict__ outp)
{
    __shared__ char s_w[3][8192];            // W triple buffer

    const int tid  = threadIdx.x;
    const int wave = tid >> 6;       // 0..7
    const int lane = tid & 63;
    const int lr   = lane & 15;
    const int lg   = lane >> 4;      // 0..3
    const int wm   = wave >> 2;      // output row (0..1)
    const int mh   = (wave >> 1) & 1;// m-half (0..1)
    const int oh   = wave & 1;       // o-half (0..1)

    const int bid0 = blockIdx.x;
    const int bid  = (bid0 & 7) * 224 + (bid0 >> 3);   // XCD swizzle (1792=8*224)
    const int n = bid / 28, h0 = (bid % 28) * 2;

    // per-lane X base: n, padded row (h0+wm), position (mh*32+lr), chan lg*8
    const char* xn = Xp + (size_t)n * NB + (size_t)(h0 + wm) * ROWB2
                   + (mh * 32 + lr) * 64 + lg * 16;
    const char* wbase = (const char*)Wp;

    // prologue: stage W K-steps 0,1
    gload16(wbase + tid * 16, s_w[0] + tid * 16);
    gload16(wbase + 8192 + tid * 16, s_w[1] + tid * 16);

    f32x4 acc[2][4];
    #pragma unroll
    for (int i = 0; i < 2; ++i)
        #pragma unroll
        for (int j = 0; j < 4; ++j)
            acc[i][j] = f32x4{0.f, 0.f, 0.f, 0.f};

    asm volatile("s_waitcnt vmcnt(1)" ::: "memory");   // W(0) complete
    __builtin_amdgcn_s_barrier();

    #pragma unroll
    for (int s = 0; s < 36; ++s) {
        const int tap = s >> 2, ks = s & 3;
        const int kh = tap / 3, kw = tap % 3;

        // A-fragments: coalesced global loads (issued first)
        short8 xa[2];
        #pragma unroll
        for (int mf = 0; mf < 2; ++mf)
            xa[mf] = *(const short8*)(xn + kh * ROWB2 + ks * PLB
                                      + (mf * 16 + kw) * 64);
        // 2-deep W prefetch into buf[(s+2)%3]
        if (s < 34)
            gload16(wbase + (size_t)(s + 2) * 8192 + tid * 16,
                    s_w[(s + 2) % 3] + tid * 16);
        __builtin_amdgcn_sched_barrier(0);

        const char* wcur = s_w[s % 3];
        short8 wb[4];
        #pragma unroll
        for (int of = 0; of < 4; ++of)
            wb[of] = *(const short8*)(wcur + (oh * 4 + of) * 1024 + lane * 16);

        __builtin_amdgcn_s_setprio(1);
        #pragma unroll
        for (int mf = 0; mf < 2; ++mf)
            #pragma unroll
            for (int of = 0; of < 4; ++of) {
                if (WHICH == 0)
                    acc[mf][of] = mfma16(xa[mf], wb[of], acc[mf][of]);
                else
                    acc[mf][of] = mfma16(wb[of], xa[mf], acc[mf][of]);
            }
        __builtin_amdgcn_s_setprio(0);

        if (s < 35) {
            __builtin_amdgcn_sched_barrier(0);
            __builtin_amdgcn_s_barrier();
            __builtin_amdgcn_sched_barrier(0);
        }
    }

    // 16x16 C/D layout (verified R1/R9-R11): col = lane&15, row = (lane>>4)*4+r
    if (WHICH == 0) {
        // D[m][o] -> plane-layout bf16: o = oh*64+of*16+lr
        char* ybase = (char*)outp + (size_t)n * NB + (size_t)(h0 + wm + 1) * ROWB2;
        #pragma unroll
        for (int of = 0; of < 4; ++of) {
            int o = oh * 64 + of * 16 + lr;
            float sh = shift[o];
            char* pl = ybase + (oh * 2 + (of >> 1)) * PLB + ((of & 1) * 16 + lr) * 2;
            #pragma unroll
            for (int mf = 0; mf < 2; ++mf) {
                #pragma unroll
                for (int r = 0; r < 4; ++r) {
                    int m = mh * 32 + mf * 16 + lg * 4 + r;
                    if (m < W) {
                        float f = acc[mf][of][r] + sh;
                        f = f > 0.f ? f : 0.f;
                        *(__hip_bfloat16*)(pl + (m + 1) * 64) = __float2bfloat16(f);
                    }
                }
            }
        }
    } else {
        // D[o][m]: o = oh*64 + of*16 + lg*4 + r, m = mh*32 + mf*16 + lr
        float* o2 = (float*)outp;
        int h = h0 + wm;
        #pragma unroll
        for (int mf = 0; mf < 2; ++mf) {
            int m = mh * 32 + mf * 16 + lr;
            if (m < W) {
                #pragma unroll
                for (int of = 0; of < 4; ++of) {
                    int ob = oh * 64 + of * 16 + lg * 4;
                    f32x4 sh = *(const f32x4*)(shift + ob);
                    #pragma unroll
                    for (int r = 0; r < 4; ++r) {
                        int o = ob + r;
                        size_t idx = ((size_t)(n * C + o) * H + h) * W + m;
                        float f = acc[mf][of][r] + sh[r] + ident[idx];
                        o2[idx] = f > 0.f ? f : 0.f;
                    }
                }
            }
        }
    }
}

// ---------------------------------------------------------------------------
extern "C" void kernel_launch(void* const* d_in, const int* in_sizes, int n_in,
                              void* d_out, int out_size, void* d_ws, size_t ws_size,
                              hipStream_t stream)
{
    const float* x  = (const float*)d_in[0];
    const float* w1 = (const float*)d_in[1];
    const float* g1 = (const float*)d_in[2];
    const float* b1 = (const float*)d_in[3];
    const float* m1 = (const float*)d_in[4];
    const float* v1 = (const float*)d_in[5];
    const float* w2 = (const float*)d_in[6];
    const float* g2 = (const float*)d_in[7];
    const float* b2 = (const float*)d_in[8];
    const float* m2 = (const float*)d_in[9];
    const float* v2 = (const float*)d_in[10];
    float* out = (float*)d_out;

    char* ws = (char*)d_ws;
    const size_t PADBUF = (size_t)NN * NB;                 // 55,115,776 B
    const size_t WBUF   = (size_t)288 * 1024;              // 294,912 B
    size_t oX  = 0;
    size_t oY  = oX + PADBUF + 32768;    // slack for overrun reads
    size_t oW1 = oY + PADBUF + 32768;
    size_t oW2 = oW1 + WBUF;
    size_t oS1 = oW2 + WBUF;
    size_t oS2 = oS1 + 512;

    char* Xp  = ws + oX;
    char* Y1  = ws + oY;
    __hip_bfloat16* W1p = (__hip_bfloat16*)(ws + oW1);
    __hip_bfloat16* W2p = (__hip_bfloat16*)(ws + oW2);
    float* s1 = (float*)(ws + oS1);
    float* s2 = (float*)(ws + oS2);

    zero_halo<<<912, 256, 0, stream>>>(Xp);
    zero_halo<<<912, 256, 0, stream>>>(Y1);

    pack_weights<<<128, 128, 0, stream>>>(w1, g1, b1, m1, v1, W1p, s1);
    pack_weights<<<128, 128, 0, stream>>>(w2, g2, b2, m2, v2, W2p, s2);
    transform_x<<<NN * H, 256, 0, stream>>>(x, Xp);

    conv3x3_kernel<0><<<NN * 28, 512, 0, stream>>>(Xp, W1p, s1, nullptr, (void*)Y1);
    conv3x3_kernel<1><<<NN * 28, 512, 0, stream>>>(Y1, W2p, s2, x, (void*)out);
}